// Round 5
// baseline (38.240 us; speedup 1.0000x reference)
//
#include <hip/hip_runtime.h>
#include <math.h>

#define N_SURF 40000
#define N_LIG  1024
#define HID    512
#define TDIM   64
#define E_MAX  131072
#define L5     5

// workspace float layout
#define WS_WP     0        // 512*3  : Wp = W_gcn[5] @ W_pos
#define WS_A3     1536     // 9      : W_surf @ Wp
#define WS_BSP    1545     // 3      : b_surf @ Wp
#define WS_BPOUT  1548     // 3      : b_gcn[5]@W_pos + b_pos
#define WS_WHBP   1552     // 64*3   : W_hbias @ Wp
#define WS_AGG    1744     // 1024*3 : sum of surface_pos over in-edges
#define WS_CNT    4816     // 1024   : in-degree
#define WS_ZERO_BEGIN 1744
#define WS_ZERO_COUNT 4096

// ---- precompute Wp = W_gcn[5] @ W_pos (512x3), zero agg/cnt ----
__global__ void k_prep1(const float* __restrict__ Wgcn, const float* __restrict__ Wpos,
                        float* __restrict__ ws) {
    int lane = threadIdx.x & 63;
    int w    = threadIdx.x >> 6;
    int k    = blockIdx.x * 4 + w;                 // 128 blocks * 4 waves = 512 rows
    const float* Wg5 = Wgcn + (size_t)L5 * HID * HID + (size_t)k * HID;
    float a0 = 0.f, a1 = 0.f, a2 = 0.f;
    for (int j = lane; j < HID; j += 64) {         // coalesced row read
        float v = Wg5[j];
        a0 += v * Wpos[j * 3 + 0];
        a1 += v * Wpos[j * 3 + 1];
        a2 += v * Wpos[j * 3 + 2];
    }
    for (int m = 32; m; m >>= 1) {
        a0 += __shfl_xor(a0, m);
        a1 += __shfl_xor(a1, m);
        a2 += __shfl_xor(a2, m);
    }
    if (lane == 0) {
        ws[WS_WP + k * 3 + 0] = a0;
        ws[WS_WP + k * 3 + 1] = a1;
        ws[WS_WP + k * 3 + 2] = a2;
    }
    int idx = blockIdx.x * blockDim.x + threadIdx.x;   // 32768 threads total
    if (idx < WS_ZERO_COUNT) ws[WS_ZERO_BEGIN + idx] = 0.f;
}

// ---- merged: blocks 0..51 = Wp-dependent folds; blocks 52..563 = edge scatter ----
// fold outputs: o<9: A3 | o<12: bsp | o<15: bpout | o<207: Whbp[o-15]
__global__ __launch_bounds__(256) void k_mid(
    const float* __restrict__ Wsurf, const float* __restrict__ bsurf,
    const float* __restrict__ bgcn,  const float* __restrict__ Wpos,
    const float* __restrict__ bpos,  const float* __restrict__ Whb,
    const int*   __restrict__ ei,    const float* __restrict__ spos,
    float* __restrict__ ws) {
    if (blockIdx.x < 52) {
        int lane = threadIdx.x & 63;
        int w    = threadIdx.x >> 6;
        int o    = blockIdx.x * 4 + w;             // 52*4 >= 207 outputs, one wave each
        if (o >= 207) return;
        float acc = 0.f;
        if (o < 9) {
            int a = o / 3, jp = o - a * 3;
            for (int k = lane; k < HID; k += 64)
                acc += Wsurf[a * HID + k] * ws[WS_WP + k * 3 + jp];
        } else if (o < 12) {
            int jp = o - 9;
            for (int k = lane; k < HID; k += 64)
                acc += bsurf[k] * ws[WS_WP + k * 3 + jp];
        } else if (o < 15) {
            int jp = o - 12;
            for (int j = lane; j < HID; j += 64)
                acc += bgcn[L5 * HID + j] * Wpos[j * 3 + jp];
        } else {
            int r = (o - 15) / 3, jp = (o - 15) % 3;
            for (int j = lane; j < HID; j += 64)
                acc += Whb[r * HID + j] * ws[WS_WP + j * 3 + jp];
        }
        for (int m = 32; m; m >>= 1) acc += __shfl_xor(acc, m);
        if (lane == 0) {
            if (o < 9)        ws[WS_A3 + o] = acc;
            else if (o < 12)  ws[WS_BSP + (o - 9)] = acc;
            else if (o < 15)  ws[WS_BPOUT + (o - 12)] = acc + bpos[o - 12];
            else              ws[WS_WHBP + (o - 15)] = acc;
        }
    } else {
        int e = (blockIdx.x - 52) * 256 + threadIdx.x;   // 512 blocks * 256 = E_MAX
        int s = ei[e];
        int d = ei[E_MAX + e];
        if (s < N_SURF && d >= N_SURF) {   // w = (~mask_lig[src]) & mask_lig[dst]
            int li = d - N_SURF;
            atomicAdd(&ws[WS_AGG + li * 3 + 0], spos[s * 3 + 0]);
            atomicAdd(&ws[WS_AGG + li * 3 + 1], spos[s * 3 + 1]);
            atomicAdd(&ws[WS_AGG + li * 3 + 2], spos[s * 3 + 2]);
            atomicAdd(&ws[WS_CNT + li], 1.0f);
        }
    }
}

// ---- per-ligand: one block per 4 nodes; weight reads amortized 4x ----
__global__ __launch_bounds__(256, 4) void k_lig(
    const float* __restrict__ lpos,  const float* __restrict__ tarr,
    const float* __restrict__ Wt1,   const float* __restrict__ bt1,
    const float* __restrict__ Wt2,   const float* __restrict__ bt2,
    const float* __restrict__ Wlig,  const float* __restrict__ blig,
    const float* __restrict__ Wgate, const float* __restrict__ bgate,
    const float* __restrict__ ws,    float* __restrict__ out)
{
    __shared__ float s_emb[4][64];
    __shared__ float s_h1[4][256];
    __shared__ float s_ht[4][64];
    __shared__ float s_out[4][4][3];   // [wave][node][3]
    int t    = threadIdx.x;
    int lane = t & 63;
    int w    = t >> 6;
    int i0   = blockIdx.x * 4;

    // emb: wave w handles node i0+w
    {
        float tt = tarr[i0 + w];
        const float coef = -0.29710775f;           // -ln(10000)/31
        float ang = tt * expf(coef * (float)(lane & 31));
        s_emb[w][lane] = (lane < 32) ? sinf(ang) : cosf(ang);
    }
    __syncthreads();
    // h1 = gelu(emb @ Wt1 + bt1): thread t owns column t for ALL 4 nodes
    {
        float b = bt1[t];
        float acc[4] = {b, b, b, b};
        #pragma unroll 16
        for (int k = 0; k < 64; ++k) {
            float wv = Wt1[k * 256 + t];
            #pragma unroll
            for (int n = 0; n < 4; ++n) acc[n] += s_emb[n][k] * wv;
        }
        #pragma unroll
        for (int n = 0; n < 4; ++n)
            s_h1[n][t] = 0.5f * acc[n] * (1.f + erff(acc[n] * 0.70710678f));
    }
    __syncthreads();
    // ht = h1 @ Wt2 + bt2: wave w -> node w, lane -> output col; 256-deep dot
    {
        float a0 = 0.f, a1 = 0.f, a2 = 0.f, a3 = 0.f;
        #pragma unroll 16
        for (int k = 0; k < 256; k += 4) {
            a0 += s_h1[w][k + 0] * Wt2[(k + 0) * 64 + lane];
            a1 += s_h1[w][k + 1] * Wt2[(k + 1) * 64 + lane];
            a2 += s_h1[w][k + 2] * Wt2[(k + 2) * 64 + lane];
            a3 += s_h1[w][k + 3] * Wt2[(k + 3) * 64 + lane];
        }
        s_ht[w][lane] = bt2[lane] + ((a0 + a1) + (a2 + a3));
    }
    __syncthreads();

    float px[4], py[4], pz[4];
    #pragma unroll
    for (int n = 0; n < 4; ++n) {
        px[n] = lpos[(i0 + n) * 3 + 0];
        py[n] = lpos[(i0 + n) * 3 + 1];
        pz[n] = lpos[(i0 + n) * 3 + 2];
    }
    float a[4][3] = {};
    // gate+fold: thread t owns cols t, t+256 for ALL 4 nodes
    #pragma unroll
    for (int r = 0; r < 2; ++r) {
        int j = r * 256 + t;
        float bg = bgate[j];
        float g[4] = {bg, bg, bg, bg};
        #pragma unroll 16
        for (int k = 0; k < 64; ++k) {
            float wv = Wgate[k * 512 + j];
            #pragma unroll
            for (int n = 0; n < 4; ++n) g[n] += s_ht[n][k] * wv;
        }
        float wl0 = Wlig[j], wl1 = Wlig[512 + j], wl2 = Wlig[1024 + j], bl = blig[j];
        float wp0 = ws[WS_WP + j * 3 + 0];
        float wp1 = ws[WS_WP + j * 3 + 1];
        float wp2 = ws[WS_WP + j * 3 + 2];
        #pragma unroll
        for (int n = 0; n < 4; ++n) {
            float p  = bl + px[n] * wl0 + py[n] * wl1 + pz[n] * wl2;
            float hl = p * (1.f / (1.f + expf(-g[n])));
            a[n][0] += hl * wp0;
            a[n][1] += hl * wp1;
            a[n][2] += hl * wp2;
        }
    }
    // + h_time @ Whbp (64x3): threads t<64, k=t
    if (t < 64) {
        float h0 = ws[WS_WHBP + t * 3 + 0];
        float h1v = ws[WS_WHBP + t * 3 + 1];
        float h2 = ws[WS_WHBP + t * 3 + 2];
        #pragma unroll
        for (int n = 0; n < 4; ++n) {
            float ht = s_ht[n][t];
            a[n][0] += ht * h0;
            a[n][1] += ht * h1v;
            a[n][2] += ht * h2;
        }
    }
    #pragma unroll
    for (int n = 0; n < 4; ++n)
        #pragma unroll
        for (int jp = 0; jp < 3; ++jp)
            for (int m = 32; m; m >>= 1) a[n][jp] += __shfl_xor(a[n][jp], m);
    if (lane == 0)
        #pragma unroll
        for (int n = 0; n < 4; ++n)
            #pragma unroll
            for (int jp = 0; jp < 3; ++jp) s_out[w][n][jp] = a[n][jp];
    __syncthreads();
    if (t < 4) {   // thread t -> node i0+t epilogue
        int n = t, i = i0 + n;
        float d  = ws[WS_CNT + i];
        float s1 = 1.f / sqrtf(1.f + d);
        float s2 = 1.f / (1.f + d);
        float c  = s1 * d;
        float ax = s1 * ws[WS_AGG + i * 3 + 0];
        float ay = s1 * ws[WS_AGG + i * 3 + 1];
        float az = s1 * ws[WS_AGG + i * 3 + 2];
        #pragma unroll
        for (int jp = 0; jp < 3; ++jp) {
            float b = s_out[0][n][jp] + s_out[1][n][jp] + s_out[2][n][jp] + s_out[3][n][jp];
            out[i * 3 + jp] = ax * ws[WS_A3 + 0 + jp] +
                              ay * ws[WS_A3 + 3 + jp] +
                              az * ws[WS_A3 + 6 + jp] +
                              c  * ws[WS_BSP + jp]    +
                              s2 * b                  +
                              ws[WS_BPOUT + jp];
        }
    }
}

extern "C" void kernel_launch(void* const* d_in, const int* in_sizes, int n_in,
                              void* d_out, int out_size, void* d_ws, size_t ws_size,
                              hipStream_t stream) {
    const float* spos  = (const float*)d_in[0];
    const float* lpos  = (const float*)d_in[1];
    const float* tarr  = (const float*)d_in[2];
    const int*   ei    = (const int*)  d_in[3];
    const float* Wsurf = (const float*)d_in[6];
    const float* bsurf = (const float*)d_in[7];
    const float* Wt1   = (const float*)d_in[8];
    const float* bt1   = (const float*)d_in[9];
    const float* Wt2   = (const float*)d_in[10];
    const float* bt2   = (const float*)d_in[11];
    const float* Wlig  = (const float*)d_in[12];
    const float* blig  = (const float*)d_in[13];
    const float* Wgate = (const float*)d_in[14];
    const float* bgate = (const float*)d_in[15];
    const float* Whb   = (const float*)d_in[16];
    const float* Wgcn  = (const float*)d_in[17];
    const float* bgcn  = (const float*)d_in[18];
    const float* Wpos  = (const float*)d_in[19];
    const float* bpos  = (const float*)d_in[20];
    float* ws  = (float*)d_ws;
    float* out = (float*)d_out;

    hipLaunchKernelGGL(k_prep1, dim3(128), dim3(256), 0, stream, Wgcn, Wpos, ws);
    hipLaunchKernelGGL(k_mid,   dim3(52 + E_MAX / 256), dim3(256), 0, stream,
                       Wsurf, bsurf, bgcn, Wpos, bpos, Whb, ei, spos, ws);
    hipLaunchKernelGGL(k_lig,   dim3(N_LIG / 4), dim3(256), 0, stream,
                       lpos, tarr, Wt1, bt1, Wt2, bt2, Wlig, blig, Wgate, bgate, ws, out);
}